// Round 2
// baseline (312.930 us; speedup 1.0000x reference)
//
#include <hip/hip_runtime.h>
#include <math.h>

#define NB 16
#define NN 2048
#define ND 256
#define BNtot (NB*NN)
#define HH 33554432u   // 2^25 = half of 16*2048*2048 (threefry counter split)

typedef __attribute__((ext_vector_type(8))) short bf16x8;
typedef __attribute__((ext_vector_type(4))) float f32x4;

// CK-style direct global->LDS DMA, 16B per lane. lds ptr must be wave-uniform.
__device__ __forceinline__ void gld16(const void* g, void* l){
  __builtin_amdgcn_global_load_lds((const __attribute__((address_space(1))) void*)g,
                                   (__attribute__((address_space(3))) void*)l, 16, 0, 0);
}

__device__ __forceinline__ unsigned rotl(unsigned v, int r){
  return __builtin_amdgcn_alignbit(v, v, 32-r);   // single v_alignbit_b32
}
__device__ __forceinline__ unsigned umaxu(unsigned a, unsigned b){ return a > b ? a : b; }
__device__ __forceinline__ unsigned uminu(unsigned a, unsigned b){ return a < b ? a : b; }

// ---------------- threefry2x32, bit-exact vs jax.random.key(42) ----------------
__device__ __forceinline__ float gumbelv(unsigned b, unsigned n, unsigned m){
  unsigned f = (b<<22) | (n<<11) | m;
  unsigned x0 = (b < 8u) ? f : (f - HH);
  unsigned x1 = x0 + HH;
  const unsigned ks0=0u, ks1=42u, ks2=0u^42u^0x1BD11BDAu;
  unsigned v0 = x0 + ks0;
  unsigned v1 = x1 + ks1;
#define TFR(r) { v0 += v1; v1 = rotl(v1,(r)); v1 ^= v0; }
  TFR(13) TFR(15) TFR(26) TFR(6)
  v0 += ks1; v1 += ks2 + 1u;
  TFR(17) TFR(29) TFR(16) TFR(24)
  v0 += ks2; v1 += ks0 + 2u;
  TFR(13) TFR(15) TFR(26) TFR(6)
  v0 += ks0; v1 += ks1 + 3u;
  TFR(17) TFR(29) TFR(16) TFR(24)
  v0 += ks1; v1 += ks2 + 4u;
  TFR(13) TFR(15) TFR(26) TFR(6)
  v0 += ks2; v1 += ks0 + 5u;
#undef TFR
  unsigned bits = (b < 8u) ? v0 : v1;
  float fl = __uint_as_float((bits>>9) | 0x3F800000u) - 1.0f;
  float u = fmaxf(1e-10f, fl + 1e-10f);
  return -logf(-logf(u));
}

// g from 23-bit key, exactly as JAX: fl = as_float(key|0x3f800000)-1
__device__ __forceinline__ float gfromkey(unsigned key){
  float fl = __uint_as_float(key | 0x3F800000u) - 1.0f;
  float u = fmaxf(1e-10f, fl + 1e-10f);
  return -logf(-logf(u));
}

// ---------------- gumbel scan body: lane-paired branchless packed top-2 ----------------
// Each thread scans 64 values of a 128-chunk (half selected by t&1); lane-pairs
// merge top-2s via shfl_xor(1). packed = (key bits 31..9 in place) | vk where vk
// is the 7-bit *descending* counter (reversed index): integer max = max gumbel,
// ties -> smallest n. Uniform trip count; injection adds folded into the
// following round's v0 add (v_add3_u32); unroll 4 => 4 independent chains (ILP).
__device__ __forceinline__ void gumbel_body(int gb, float* __restrict__ pcv, int* __restrict__ pci){
  int t    = gb*256 + (int)threadIdx.x;
  int half = t & 1;
  int m    = (t >> 1) & 2047;
  int bl   = (t >> 12) & 7;
  int nq   = t >> 15;                        // 0..15, chunk of 128
  int chunkbase = nq << 7;
  int nstart = chunkbase + (half << 6);      // this thread's 64 values
  unsigned x0 = ((unsigned)bl << 22) | ((unsigned)nstart << 11) | (unsigned)m;
  const unsigned KS2 = 42u ^ 0x1BD11BDAu;
  unsigned a1=0, a2=0, c1=0, c2=0;           // packed top-2 (A=batch bl, C=batch bl+8)
  unsigned vk = (unsigned)(127 - (half<<6)); // descending counter; n = chunkbase + 127 - vk
#define TFR(r)       { v0 += v1; v1 = rotl(v1,(r)); v1 ^= v0; }
#define TFRI(r, inj) { v0 += v1 + (inj); v1 = rotl(v1,(r)); v1 ^= v0; }
  #pragma unroll 4
  for (int j = 0; j < 64; ++j){
    unsigned v0 = x0;
    unsigned v1 = x0 + (HH + 42u);
    TFR(13) TFR(15) TFR(26) TFR(6)
    v1 += KS2 + 1u;
    TFRI(17, 42u) TFR(29) TFR(16) TFR(24)
    v1 += 2u;
    TFRI(13, KS2) TFR(15) TFR(26) TFR(6)
    v1 += 42u + 3u;
    TFR(17) TFR(29) TFR(16) TFR(24)     /* v0 += 0 before this group */
    v1 += KS2 + 4u;
    TFRI(13, 42u) TFR(15) TFR(26) TFR(6)
    v0 += KS2; v1 += 5u;
    // (v0 & ~0x1FF) | (vk & 0x1FF): bfi-shaped, single v_bfi_b32
    unsigned pa = (v0 & 0xFFFFFE00u) | (vk & 0x1FFu);
    unsigned pb = (v1 & 0xFFFFFE00u) | (vk & 0x1FFu);
    unsigned ta = uminu(pa, a1);
    a1 = umaxu(pa, a1);
    a2 = umaxu(ta, a2);
    unsigned tc = uminu(pb, c1);
    c1 = umaxu(pb, c1);
    c2 = umaxu(tc, c2);
    x0 += 2048u;
    vk -= 1u;
  }
#undef TFR
#undef TFRI
  // merge with partner lane (other half of the chunk)
  unsigned p1 = __shfl_xor((int)a1, 1), p2 = __shfl_xor((int)a2, 1);
  unsigned q1 = __shfl_xor((int)c1, 1), q2 = __shfl_xor((int)c2, 1);
  unsigned A1 = umaxu(a1, p1);
  unsigned A2 = umaxu(uminu(a1, p1), umaxu(a2, p2));
  unsigned C1 = umaxu(c1, q1);
  unsigned C2 = umaxu(uminu(c1, q1), umaxu(c2, q2));
  if (half == 0){
    int baseA = (((nq*NB + bl  )*NN + m) << 1);
    int baseB = (((nq*NB + bl+8)*NN + m) << 1);
    pcv[baseA+0] = gfromkey(A1 >> 9); pci[baseA+0] = chunkbase + 127 - (int)(A1 & 127u);
    pcv[baseA+1] = gfromkey(A2 >> 9); pci[baseA+1] = chunkbase + 127 - (int)(A2 & 127u);
    pcv[baseB+0] = gfromkey(C1 >> 9); pci[baseB+0] = chunkbase + 127 - (int)(C1 & 127u);
    pcv[baseB+1] = gfromkey(C2 >> 9); pci[baseB+1] = chunkbase + 127 - (int)(C2 & 127u);
  }
}

// standalone wrapper (middle tier)
__launch_bounds__(256)
__global__ void kgumbel(float* __restrict__ pcv, int* __restrict__ pci){
  gumbel_body(blockIdx.x, pcv, pci);
}

// ---------------- row norms (middle tier) ----------------
__global__ void knorms(const float* __restrict__ LLF, const float* __restrict__ HLF,
                       float* __restrict__ nl, float* __restrict__ nh){
  int row = blockIdx.x;
  int wave = threadIdx.x >> 6;
  int lane = threadIdx.x & 63;
  const float* src = wave ? HLF : LLF;
  float4 v = ((const float4*)(src + (size_t)row*ND))[lane];
  float s = v.x*v.x + v.y*v.y + v.z*v.z + v.w*v.w;
  for (int o=32;o;o>>=1) s += __shfl_down(s,o);
  if (lane==0) (wave? nh: nl)[row] = sqrtf(s);
}

// ---------------- fused kernel 1: prep (HBM-bound, ~8% issue) || ALL gumbel (VALU-bound) ----------------
// 18432 blocks = 2048 groups of 9: 1 gumbel + 8 prep, uniformly interleaved so every
// CU carries a pipe-complementary mix from t=0. prep blocks retire in ~us and are
// backfilled; gumbel density self-balances to full residency as prep drains.
// LDS=0, low VGPR -> 8 blocks/CU.
__launch_bounds__(256)
__global__ void kfuse1(const float* __restrict__ LLF, const float* __restrict__ HLF,
                       ushort* __restrict__ Abf, ushort* __restrict__ Bbf,
                       float* __restrict__ nl, float* __restrict__ nh,
                       float* __restrict__ pcv, int* __restrict__ pci){
  int bid = blockIdx.x;
  int g = bid / 9, r = bid - g*9;
  if (r == 0){ gumbel_body(g, pcv, pci); return; }
  int pid = g*8 + (r-1);                     // 0..16383
  int px  = pid & 8191;
  int py  = pid >> 13;
  int w    = threadIdx.x >> 6;
  int lane = threadIdx.x & 63;
  int row = px*4 + w;                        // global row 0..BNtot-1
  const float* src = py ? HLF : LLF;
  ushort* dst      = py ? Bbf : Abf;
  float4 v = ((const float4*)(src + (size_t)row*ND))[lane];
  float s = v.x*v.x + v.y*v.y + v.z*v.z + v.w*v.w;
  for (int o=32;o;o>>=1) s += __shfl_down(s,o);
  if (lane==0) (py ? nh : nl)[row] = sqrtf(s);
  uint2 u;
  u.x = (__float_as_uint(v.y)&0xFFFF0000u)|(__float_as_uint(v.x)>>16);
  u.y = (__float_as_uint(v.w)&0xFFFF0000u)|(__float_as_uint(v.z)>>16);
  int b = row >> 11, nloc = row & 2047;
  int k = lane << 2;
  int ck = k >> 6;
  int j  = k & 63;
  int qi = j >> 3;
  size_t off = (size_t)b*524288 + (size_t)ck*131072 + (size_t)nloc*64
             + ((qi ^ (nloc & 7)) << 3) + (j & 7);
  *(uint2*)(dst + off) = u;
}

// ---------------- bf16 MFMA GEMM with global_load_lds staging (standalone again) ----------------
#define K1 0.09016844f   /* 0.0625 * log2(e) */
__launch_bounds__(256)
__global__ void kgemm_dma(const ushort* __restrict__ Abf, const ushort* __restrict__ Bbf,
                          const float* __restrict__ nl, const float* __restrict__ nh,
                          float* __restrict__ partS){
  __shared__ ushort As[128*64];   // 16 KB, [row][64] with XOR-swizzled quads
  __shared__ ushort Bs[128*64];
  __shared__ float colsum[128];
  const int b  = blockIdx.z;
  const int n0 = blockIdx.y << 7;
  const int m0 = blockIdx.x << 7;
  const int tid  = threadIdx.x;
  const int lane = tid & 63;
  const int w    = tid >> 6;
  const int wn   = w >> 1, wm = w & 1;
  const int quad = lane >> 4, l15 = lane & 15;
  if (tid < 128) colsum[tid] = 0.0f;

  const ushort* Ab = Abf + (size_t)b*524288;
  const ushort* Bb = Bbf + (size_t)b*524288;

  f32x4 acc[4][4];
  #pragma unroll
  for (int i=0;i<4;i++)
    #pragma unroll
    for (int j=0;j<4;j++) acc[i][j] = (f32x4){0.f,0.f,0.f,0.f};

  for (int ck=0; ck<4; ck++){
    __syncthreads();
    const ushort* ga = Ab + (size_t)ck*131072 + (size_t)n0*64;  // 16 KB contiguous
    const ushort* gb = Bb + (size_t)ck*131072 + (size_t)m0*64;
    #pragma unroll
    for (int t=0;t<4;t++){
      int seg = (w*4 + t) * 512;              // 512 ushorts = 1 KB per wave-load
      gld16(ga + seg + lane*8, &As[seg]);
      gld16(gb + seg + lane*8, &Bs[seg]);
    }
    __syncthreads();
    #pragma unroll
    for (int ks=0; ks<64; ks+=32){
      bf16x8 af[4], bf[4];
      #pragma unroll
      for (int t=0;t<4;t++){
        int R = wn*64 + t*16 + l15;
        af[t] = *(const bf16x8*)(&As[R*64 + ((((ks>>3)+quad) ^ (R&7))<<3)]);
      }
      #pragma unroll
      for (int t=0;t<4;t++){
        int R = wm*64 + t*16 + l15;
        bf[t] = *(const bf16x8*)(&Bs[R*64 + ((((ks>>3)+quad) ^ (R&7))<<3)]);
      }
      #pragma unroll
      for (int ti=0;ti<4;ti++)
        #pragma unroll
        for (int tj=0;tj<4;tj++)
          acc[ti][tj] = __builtin_amdgcn_mfma_f32_16x16x32_bf16(af[ti], bf[tj], acc[ti][tj], 0, 0, 0);
    }
  }

  float an[4][4];
  #pragma unroll
  for (int ti=0;ti<4;ti++)
    #pragma unroll
    for (int r=0;r<4;r++)
      an[ti][r] = K1 / nl[b*NN + n0 + wn*64 + ti*16 + quad*4 + r];
  float bm[4];
  #pragma unroll
  for (int tj=0;tj<4;tj++)
    bm[tj] = 1.0f / nh[b*NN + m0 + wm*64 + tj*16 + l15];
  #pragma unroll
  for (int tj=0;tj<4;tj++){
    float s = 0.0f;
    #pragma unroll
    for (int ti=0;ti<4;ti++)
      #pragma unroll
      for (int r=0;r<4;r++)
        s += __builtin_amdgcn_exp2f(acc[ti][tj][r]*an[ti][r]*bm[tj] - K1);
    s += __shfl_down(s, 32);
    s += __shfl_down(s, 16);
    if (lane < 16) atomicAdd(&colsum[wm*64 + tj*16 + l15], s);
  }
  __syncthreads();
  if (tid < 128)
    partS[(size_t)blockIdx.y*BNtot + b*NN + m0 + tid] = colsum[tid];
}

// ---------------- middle-tier GEMM (in-kernel conversion) ----------------
__launch_bounds__(256)
__global__ void kgemm_mfma(const float* __restrict__ LLF, const float* __restrict__ HLF,
                           const float* __restrict__ nl, const float* __restrict__ nh,
                           float* __restrict__ partS){
  __shared__ ushort As[128][72];
  __shared__ ushort Bs[128][72];
  __shared__ float colsum[128];
  const int b  = blockIdx.z;
  const int n0 = blockIdx.y << 7;
  const int m0 = blockIdx.x << 7;
  const float* Ab = LLF + (size_t)b*NN*ND;
  const float* Bb = HLF + (size_t)b*NN*ND;
  const int tid  = threadIdx.x;
  const int lane = tid & 63;
  const int w    = tid >> 6;
  const int wn   = w >> 1, wm = w & 1;
  const int quad = lane >> 4, l15 = lane & 15;
  if (tid < 128) colsum[tid] = 0.0f;

  f32x4 acc[4][4];
  #pragma unroll
  for (int i=0;i<4;i++)
    #pragma unroll
    for (int j=0;j<4;j++) acc[i][j] = (f32x4){0.f,0.f,0.f,0.f};

  const int rbase = tid >> 3;
  const int kq    = (tid & 7) << 3;

  for (int ck=0; ck<4; ck++){
    const int k0 = ck << 6;
    __syncthreads();
    #pragma unroll
    for (int pi=0; pi<4; pi++){
      int row = rbase + (pi<<5);
      const float* pa = Ab + (size_t)(n0+row)*ND + k0 + kq;
      float4 a0 = *(const float4*)pa;
      float4 a1 = *(const float4*)(pa+4);
      uint4 ua;
      ua.x = (__float_as_uint(a0.y)&0xFFFF0000u)|(__float_as_uint(a0.x)>>16);
      ua.y = (__float_as_uint(a0.w)&0xFFFF0000u)|(__float_as_uint(a0.z)>>16);
      ua.z = (__float_as_uint(a1.y)&0xFFFF0000u)|(__float_as_uint(a1.x)>>16);
      ua.w = (__float_as_uint(a1.w)&0xFFFF0000u)|(__float_as_uint(a1.z)>>16);
      *(uint4*)(&As[row][kq]) = ua;
      const float* pb = Bb + (size_t)(m0+row)*ND + k0 + kq;
      float4 b0 = *(const float4*)pb;
      float4 b1 = *(const float4*)(pb+4);
      uint4 ub;
      ub.x = (__float_as_uint(b0.y)&0xFFFF0000u)|(__float_as_uint(b0.x)>>16);
      ub.y = (__float_as_uint(b0.w)&0xFFFF0000u)|(__float_as_uint(b0.z)>>16);
      ub.z = (__float_as_uint(b1.y)&0xFFFF0000u)|(__float_as_uint(b1.x)>>16);
      ub.w = (__float_as_uint(b1.w)&0xFFFF0000u)|(__float_as_uint(b1.z)>>16);
      *(uint4*)(&Bs[row][kq]) = ub;
    }
    __syncthreads();
    #pragma unroll
    for (int ks=0; ks<64; ks+=32){
      bf16x8 af[4], bf[4];
      #pragma unroll
      for (int t=0;t<4;t++)
        af[t] = *(const bf16x8*)(&As[wn*64 + t*16 + l15][ks + quad*8]);
      #pragma unroll
      for (int t=0;t<4;t++)
        bf[t] = *(const bf16x8*)(&Bs[wm*64 + t*16 + l15][ks + quad*8]);
      #pragma unroll
      for (int ti=0;ti<4;ti++)
        #pragma unroll
        for (int tj=0;tj<4;tj++)
          acc[ti][tj] = __builtin_amdgcn_mfma_f32_16x16x32_bf16(af[ti], bf[tj], acc[ti][tj], 0, 0, 0);
    }
  }

  float an[4][4];
  #pragma unroll
  for (int ti=0;ti<4;ti++)
    #pragma unroll
    for (int r=0;r<4;r++)
      an[ti][r] = K1 / nl[b*NN + n0 + wn*64 + ti*16 + quad*4 + r];
  float bm[4];
  #pragma unroll
  for (int tj=0;tj<4;tj++)
    bm[tj] = 1.0f / nh[b*NN + m0 + wm*64 + tj*16 + l15];
  #pragma unroll
  for (int tj=0;tj<4;tj++){
    float s = 0.0f;
    #pragma unroll
    for (int ti=0;ti<4;ti++)
      #pragma unroll
      for (int r=0;r<4;r++)
        s += __builtin_amdgcn_exp2f(acc[ti][tj][r]*an[ti][r]*bm[tj] - K1);
    s += __shfl_down(s, 32);
    s += __shfl_down(s, 16);
    if (lane < 16) atomicAdd(&colsum[wm*64 + tj*16 + l15], s);
  }
  __syncthreads();
  if (tid < 128)
    partS[(size_t)blockIdx.y*BNtot + b*NN + m0 + tid] = colsum[tid];
}

// ---------------- resolve: exact argmax among windowed candidates (inlines partS sum) ----------------
__launch_bounds__(256)
__global__ void kresolve(const float* __restrict__ LLF, const float* __restrict__ HLF,
                         const float* __restrict__ nl, const float* __restrict__ nh,
                         const float* __restrict__ partS,
                         const float* __restrict__ pcv, const int* __restrict__ pci,
                         int* __restrict__ idx){
  int w    = threadIdx.x >> 6;               // wave within block
  int lane = threadIdx.x & 63;
  int g = blockIdx.x*4 + w;                  // b*NN+m
  int b = g >> 11, m = g & 2047;
  // softmax denominator: sum 16 partial tiles (was kScomb)
  float ps = (lane < 16) ? partS[(size_t)lane*BNtot + g] : 0.0f;
  ps += __shfl_down(ps, 8);
  ps += __shfl_down(ps, 4);
  ps += __shfl_down(ps, 2);
  ps += __shfl_down(ps, 1);
  float invS = 1.0f / __shfl(ps, 0);
  float pv = -INFINITY; int pn = 0;
  if (lane < 32){                            // nq = lane>>1, rank = lane&1
    int base = ((((lane>>1)*NB + b)*NN + m) << 1) + (lane & 1);
    pv = pcv[base]; pn = pci[base];
  }
  float gmax = pv;
  for (int o=32;o;o>>=1) gmax = fmaxf(gmax, __shfl_down(gmax,o));
  gmax = __shfl(gmax, 0);
  unsigned long long mask = __ballot(pv >= gmax - 8e-5f);
  mask &= 0xFFFFFFFFull;
  float4 h = ((const float4*)(HLF + (size_t)g*ND))[lane];   // loop-invariant row m
  float nhg = nh[g];
  float bestQ = -INFINITY; int bestN = 1<<30;
  while (mask){
    int src = __builtin_ctzll(mask); mask &= mask-1;
    int   n  = __shfl(pn, src);
    float gv = __shfl(pv, src);
    float4 a = ((const float4*)(LLF + ((size_t)b*NN + n)*ND))[lane];
    float d = a.x*h.x + a.y*h.y + a.z*h.z + a.w*h.w;
    for (int o=32;o;o>>=1) d += __shfl_down(d,o);
    d = __shfl(d, 0);
    float sim = (d / fmaxf(nl[b*NN+n]*nhg, 1e-8f)) * 0.0625f;
    float q = expf(sim - 0.0625f)*invS + gv;
    if (q > bestQ || (q == bestQ && n < bestN)){ bestQ = q; bestN = n; }
  }
  if (lane==0) idx[g] = bestN;
}

// ---------------- last-resort fallback (tiny ws) ----------------
__launch_bounds__(256)
__global__ void kstats(const float* __restrict__ A, const float* __restrict__ Bm,
                       const float* __restrict__ nl, const float* __restrict__ nh,
                       float* __restrict__ Mout, float* __restrict__ Sinv){
  __shared__ float As[64][33];
  __shared__ float Bs[64][33];
  __shared__ float Cs[64][65];
  const int b  = blockIdx.x >> 5;
  const int m0 = (blockIdx.x & 31) << 6;
  const float* Ab = A  + (size_t)b*NN*ND;
  const float* Bb = Bm + (size_t)b*NN*ND;
  const int tid = threadIdx.x;
  const int tx = tid & 15, ty = tid >> 4;
  float nhv[4];
  #pragma unroll
  for (int j=0;j<4;j++) nhv[j] = nh[b*NN + m0 + tx*4 + j];
  float Mr = -INFINITY, Sr = 0.0f;
  for (int nt=0; nt<NN; nt+=64){
    float acc[4][4] = {{0.f,0.f,0.f,0.f},{0.f,0.f,0.f,0.f},{0.f,0.f,0.f,0.f},{0.f,0.f,0.f,0.f}};
    for (int kc=0; kc<ND; kc+=32){
      __syncthreads();
      #pragma unroll
      for (int s=0;s<2;s++){
        int f = tid + (s<<8);
        int r = f >> 3;
        int c = (f & 7) << 2;
        float4 va = *(const float4*)(Ab + (size_t)(nt+r)*ND + kc + c);
        As[r][c]=va.x; As[r][c+1]=va.y; As[r][c+2]=va.z; As[r][c+3]=va.w;
        float4 vb = *(const float4*)(Bb + (size_t)(m0+r)*ND + kc + c);
        Bs[r][c]=vb.x; Bs[r][c+1]=vb.y; Bs[r][c+2]=vb.z; Bs[r][c+3]=vb.w;
      }
      __syncthreads();
      #pragma unroll 4
      for (int k=0;k<32;k++){
        float a0=As[ty*4+0][k], a1=As[ty*4+1][k], a2=As[ty*4+2][k], a3=As[ty*4+3][k];
        float b0=Bs[tx*4+0][k], b1=Bs[tx*4+1][k], b2=Bs[tx*4+2][k], b3=Bs[tx*4+3][k];
        acc[0][0]+=a0*b0; acc[0][1]+=a0*b1; acc[0][2]+=a0*b2; acc[0][3]+=a0*b3;
        acc[1][0]+=a1*b0; acc[1][1]+=a1*b1; acc[1][2]+=a1*b2; acc[1][3]+=a1*b3;
        acc[2][0]+=a2*b0; acc[2][1]+=a2*b1; acc[2][2]+=a2*b2; acc[2][3]+=a2*b3;
        acc[3][0]+=a3*b0; acc[3][1]+=a3*b1; acc[3][2]+=a3*b2; acc[3][3]+=a3*b3;
      }
    }
    float nlv[4];
    #pragma unroll
    for (int i=0;i<4;i++) nlv[i] = nl[b*NN + nt + ty*4 + i];
    __syncthreads();
    #pragma unroll
    for (int i=0;i<4;i++)
      #pragma unroll
      for (int j=0;j<4;j++){
        float denom = fmaxf(nlv[i]*nhv[j], 1e-8f);
        Cs[ty*4+i][tx*4+j] = (acc[i][j]/denom)*0.0625f;
      }
    __syncthreads();
    if (tid < 64){
      float tmax = -INFINITY;
      #pragma unroll 8
      for (int r=0;r<64;r++) tmax = fmaxf(tmax, Cs[r][tid]);
      float newM = fmaxf(Mr, tmax);
      float s = 0.0f;
      #pragma unroll 4
      for (int r=0;r<64;r++) s += expf(Cs[r][tid]-newM);
      Sr = Sr*expf(Mr-newM) + s;
      Mr = newM;
    }
  }
  if (tid < 64){
    Mout[b*NN+m0+tid] = Mr;
    Sinv[b*NN+m0+tid] = 1.0f/Sr;
  }
}

__launch_bounds__(256)
__global__ void kargmax(const float* __restrict__ A, const float* __restrict__ Bm,
                        const float* __restrict__ nl, const float* __restrict__ nh,
                        const float* __restrict__ Mv, const float* __restrict__ Sv,
                        int* __restrict__ idxout){
  __shared__ float As[64][33];
  __shared__ float Bs[64][33];
  __shared__ float Vs[16][64];
  __shared__ int   Is[16][64];
  const int b  = blockIdx.x >> 5;
  const int m0 = (blockIdx.x & 31) << 6;
  const float* Ab = A  + (size_t)b*NN*ND;
  const float* Bb = Bm + (size_t)b*NN*ND;
  const int tid = threadIdx.x;
  const int tx = tid & 15, ty = tid >> 4;
  float nhv[4], Mj[4], iSj[4];
  #pragma unroll
  for (int j=0;j<4;j++){
    int m = m0 + tx*4 + j;
    nhv[j] = nh[b*NN + m];
    Mj[j]  = Mv[b*NN + m];
    iSj[j] = Sv[b*NN + m];
  }
  float bestV = -INFINITY; int bestN = 0;
  for (int nt=0; nt<NN; nt+=64){
    float acc[4][4] = {{0.f,0.f,0.f,0.f},{0.f,0.f,0.f,0.f},{0.f,0.f,0.f,0.f},{0.f,0.f,0.f,0.f}};
    for (int kc=0; kc<ND; kc+=32){
      __syncthreads();
      #pragma unroll
      for (int s=0;s<2;s++){
        int f = tid + (s<<8);
        int r = f >> 3;
        int c = (f & 7) << 2;
        float4 va = *(const float4*)(Ab + (size_t)(nt+r)*ND + kc + c);
        As[r][c]=va.x; As[r][c+1]=va.y; As[r][c+2]=va.z; As[r][c+3]=va.w;
        float4 vb = *(const float4*)(Bb + (size_t)(m0+r)*ND + kc + c);
        Bs[r][c]=vb.x; Bs[r][c+1]=vb.y; Bs[r][c+2]=vb.z; Bs[r][c+3]=vb.w;
      }
      __syncthreads();
      #pragma unroll 4
      for (int k=0;k<32;k++){
        float a0=As[ty*4+0][k], a1=As[ty*4+1][k], a2=As[ty*4+2][k], a3=As[ty*4+3][k];
        float b0=Bs[tx*4+0][k], b1=Bs[tx*4+1][k], b2=Bs[tx*4+2][k], b3=Bs[tx*4+3][k];
        acc[0][0]+=a0*b0; acc[0][1]+=a0*b1; acc[0][2]+=a0*b2; acc[0][3]+=a0*b3;
        acc[1][0]+=a1*b0; acc[1][1]+=a1*b1; acc[1][2]+=a1*b2; acc[1][3]+=a1*b3;
        acc[2][0]+=a2*b0; acc[2][1]+=a2*b1; acc[2][2]+=a2*b2; acc[2][3]+=a2*b3;
        acc[3][0]+=a3*b0; acc[3][1]+=a3*b1; acc[3][2]+=a3*b2; acc[3][3]+=a3*b3;
      }
    }
    float nlv[4];
    #pragma unroll
    for (int i=0;i<4;i++) nlv[i] = nl[b*NN + nt + ty*4 + i];
    float lv[4]; int li[4];
    #pragma unroll
    for (int j=0;j<4;j++){ lv[j] = -INFINITY; li[j] = 0; }
    #pragma unroll
    for (int i=0;i<4;i++){
      int n = nt + ty*4 + i;
      #pragma unroll
      for (int j=0;j<4;j++){
        float denom = fmaxf(nlv[i]*nhv[j], 1e-8f);
        float sim = (acc[i][j]/denom)*0.0625f;
        float p = expf(sim - Mj[j]) * iSj[j];
        float v = p + gumbelv((unsigned)b, (unsigned)n, (unsigned)(m0 + tx*4 + j));
        if (v > lv[j]) { lv[j] = v; li[j] = n; }
      }
    }
    __syncthreads();
    #pragma unroll
    for (int j=0;j<4;j++){ Vs[ty][tx*4+j]=lv[j]; Is[ty][tx*4+j]=li[j]; }
    __syncthreads();
    if (tid < 64){
      #pragma unroll 4
      for (int t=0;t<16;t++){
        float v = Vs[t][tid];
        if (v > bestV){ bestV = v; bestN = Is[t][tid]; }
      }
    }
  }
  if (tid < 64) idxout[b*NN + m0 + tid] = bestN;
}

// ---------------- shared tail kernels ----------------
__global__ void ksort(const int* __restrict__ idx, int* __restrict__ cntg,
                      int* __restrict__ offg, int* __restrict__ sl){
  __shared__ int c[NN];
  __shared__ int part[256];
  int b = blockIdx.x, tid = threadIdx.x;
  for (int v=tid; v<NN; v+=256) c[v]=0;
  __syncthreads();
  for (int j=tid; j<NN; j+=256) atomicAdd(&c[idx[b*NN+j]], 1);
  __syncthreads();
  int base = tid*8, s=0, lc[8];
  #pragma unroll
  for (int k=0;k<8;k++){ lc[k]=c[base+k]; s+=lc[k]; }
  part[tid]=s; __syncthreads();
  for (int o=1;o<256;o<<=1){
    int v = (tid>=o)? part[tid-o] : 0;
    __syncthreads();
    part[tid]+=v;
    __syncthreads();
  }
  int run = part[tid]-s;
  #pragma unroll
  for (int k=0;k<8;k++){
    int v = base+k;
    cntg[b*NN+v]=lc[k];
    offg[b*NN+v]=run;
    for (int j=0;j<lc[k];j++) sl[b*NN+run+j]=v;
    run += lc[k];
  }
}

__global__ void kw(const float* __restrict__ LLF, const float* __restrict__ HLF,
                   const float* __restrict__ nl, const float* __restrict__ nh,
                   const int* __restrict__ sl, float* __restrict__ w){
  int g = blockIdx.x*4 + (threadIdx.x>>6);
  int lane = threadIdx.x & 63;
  int b = g >> 11;
  int s = sl[g];
  float4 a = ((const float4*)(HLF + ((size_t)b*NN + s)*ND))[lane];
  float4 l = ((const float4*)(LLF + (size_t)g*ND))[lane];
  float d = a.x*l.x + a.y*l.y + a.z*l.z + a.w*l.w;
  for (int o=32;o;o>>=1) d += __shfl_down(d,o);
  if (lane==0){
    float denom = fmaxf(nh[b*NN+s]*nl[g], 1e-8f);
    w[g] = d/denom;
  }
}

__global__ void knoise(const float* __restrict__ w, float* __restrict__ nz){
  int b = blockIdx.x, tid = threadIdx.x;
  __shared__ float sred[4];
  float x[8]; float mx = -INFINITY;
  #pragma unroll
  for (int k=0;k<8;k++){ x[k] = w[b*NN + tid*8 + k] / 0.1f; mx = fmaxf(mx, x[k]); }
  for (int o=32;o;o>>=1) mx = fmaxf(mx, __shfl_down(mx,o));
  mx = __shfl(mx, 0);
  if ((tid&63)==0) sred[tid>>6] = mx;
  __syncthreads();
  mx = fmaxf(fmaxf(sred[0],sred[1]), fmaxf(sred[2],sred[3]));
  __syncthreads();
  float e[8]; float s = 0.f;
  #pragma unroll
  for (int k=0;k<8;k++){ e[k] = expf(x[k]-mx); s += e[k]; }
  for (int o=32;o;o>>=1) s += __shfl_down(s,o);
  s = __shfl(s, 0);
  if ((tid&63)==0) sred[tid>>6] = s;
  __syncthreads();
  s = sred[0]+sred[1]+sred[2]+sred[3];
  #pragma unroll
  for (int k=0;k<8;k++) nz[b*NN + tid*8 + k] = e[k]/s;
}

__global__ void kfinal(const float* __restrict__ LLF, const float* __restrict__ HLF,
                       const int* __restrict__ cnt, const int* __restrict__ off,
                       const float* __restrict__ nz, float* __restrict__ out){
  int row = blockIdx.x;
  int lane = threadIdx.x;
  int b = row >> 11;
  float4 h = ((const float4*)(HLF + (size_t)row*ND))[lane];
  int c = cnt[row];
  if (c > 0){
    int i = off[row] + c - 1;
    float ns = nz[b*NN + i];
    float4 l = ((const float4*)(LLF + ((size_t)(b*NN + i))*ND))[lane];
    h.x += l.x*ns; h.y += l.y*ns; h.z += l.z*ns; h.w += l.w*ns;
  }
  ((float4*)(out + (size_t)row*ND))[lane] = h;
}

extern "C" void kernel_launch(void* const* d_in, const int* in_sizes, int n_in,
                              void* d_out, int out_size, void* d_ws, size_t ws_size,
                              hipStream_t stream){
  const float* LLF = (const float*)d_in[0];
  const float* HLF = (const float*)d_in[1];
  float* out = (float*)d_out;
  float* ws = (float*)d_ws;

  float* nl  = ws;
  float* nh  = ws + 1*(size_t)BNtot;
  float* iS  = ws + 2*(size_t)BNtot;
  int*   idx = (int*)(ws + 3*(size_t)BNtot);
  int*   cnt = (int*)(ws + 4*(size_t)BNtot);
  int*   off = (int*)(ws + 5*(size_t)BNtot);
  int*   sl  = (int*)(ws + 6*(size_t)BNtot);
  float* wv  = ws + 7*(size_t)BNtot;
  float* nz  = ws + 8*(size_t)BNtot;
  float* partS = ws + 9*(size_t)BNtot;                 // 16*BNtot
  float* pcv   = partS + 16*(size_t)BNtot;             // 32*BNtot (16 chunks x 2 ranks)
  int*   pci   = (int*)(pcv + 32*(size_t)BNtot);       // 32*BNtot
  ushort* Abf  = (ushort*)(pci + 32*(size_t)BNtot);    // BNtot*256 bf16 (16.7 MB)
  ushort* Bbf  = Abf + (size_t)BNtot*ND;
  const size_t needBytes1 = (9 + 16 + 32 + 32) * (size_t)BNtot * 4;           // ~11.7 MB
  const size_t needBytes2 = needBytes1 + 2 * (size_t)BNtot * ND * 2;          // ~45.2 MB

  if (ws_size >= needBytes2){
    // [prep || ALL gumbel, 1:8 interleaved] -> gemm -> resolve (inlines Scomb)
    hipLaunchKernelGGL(kfuse1,  dim3(18432),     dim3(256), 0, stream, LLF, HLF, Abf, Bbf, nl, nh, pcv, pci);
    hipLaunchKernelGGL(kgemm_dma,dim3(16,16,16), dim3(256), 0, stream, Abf, Bbf, nl, nh, partS);
    hipLaunchKernelGGL(kresolve,dim3(BNtot/4),   dim3(256), 0, stream, LLF, HLF, nl, nh, partS, pcv, pci, idx);
  } else if (ws_size >= needBytes1){
    hipLaunchKernelGGL(knorms,   dim3(BNtot),      dim3(128), 0, stream, LLF, HLF, nl, nh);
    hipLaunchKernelGGL(kgemm_mfma,dim3(16,16,16),  dim3(256), 0, stream, LLF, HLF, nl, nh, partS);
    hipLaunchKernelGGL(kgumbel,  dim3(2048),       dim3(256), 0, stream, pcv, pci);
    hipLaunchKernelGGL(kresolve, dim3(BNtot/4),    dim3(256), 0, stream, LLF, HLF, nl, nh, partS, pcv, pci, idx);
  } else {
    float* Mv = ws + 9*(size_t)BNtot;
    hipLaunchKernelGGL(knorms,   dim3(BNtot),      dim3(128), 0, stream, LLF, HLF, nl, nh);
    hipLaunchKernelGGL(kstats,   dim3(NB*32),      dim3(256), 0, stream, LLF, HLF, nl, nh, Mv, iS);
    hipLaunchKernelGGL(kargmax,  dim3(NB*32),      dim3(256), 0, stream, LLF, HLF, nl, nh, Mv, iS, idx);
  }

  hipLaunchKernelGGL(ksort,  dim3(NB),      dim3(256), 0, stream, idx, cnt, off, sl);
  hipLaunchKernelGGL(kw,     dim3(BNtot/4), dim3(256), 0, stream, LLF, HLF, nl, nh, sl, wv);
  hipLaunchKernelGGL(knoise, dim3(NB),      dim3(256), 0, stream, wv, nz);
  hipLaunchKernelGGL(kfinal, dim3(BNtot),   dim3(64),  0, stream, LLF, HLF, cnt, off, nz, out);
}

// Round 3
// 284.007 us; speedup vs baseline: 1.1018x; 1.1018x over previous
//
#include <hip/hip_runtime.h>
#include <math.h>

#define NB 16
#define NN 2048
#define ND 256
#define BNtot (NB*NN)
#define HH 33554432u   // 2^25 = half of 16*2048*2048 (threefry counter split)

typedef __attribute__((ext_vector_type(8))) short bf16x8;
typedef __attribute__((ext_vector_type(4))) float f32x4;

// CK-style direct global->LDS DMA, 16B per lane. lds ptr must be wave-uniform.
__device__ __forceinline__ void gld16(const void* g, void* l){
  __builtin_amdgcn_global_load_lds((const __attribute__((address_space(1))) void*)g,
                                   (__attribute__((address_space(3))) void*)l, 16, 0, 0);
}

__device__ __forceinline__ unsigned rotl(unsigned v, int r){
  return __builtin_amdgcn_alignbit(v, v, 32-r);   // single v_alignbit_b32
}
__device__ __forceinline__ unsigned umaxu(unsigned a, unsigned b){ return a > b ? a : b; }
__device__ __forceinline__ unsigned uminu(unsigned a, unsigned b){ return a < b ? a : b; }

// ---------------- threefry2x32, bit-exact vs jax.random.key(42) ----------------
__device__ __forceinline__ float gumbelv(unsigned b, unsigned n, unsigned m){
  unsigned f = (b<<22) | (n<<11) | m;
  unsigned x0 = (b < 8u) ? f : (f - HH);
  unsigned x1 = x0 + HH;
  const unsigned ks0=0u, ks1=42u, ks2=0u^42u^0x1BD11BDAu;
  unsigned v0 = x0 + ks0;
  unsigned v1 = x1 + ks1;
#define TFR(r) { v0 += v1; v1 = rotl(v1,(r)); v1 ^= v0; }
  TFR(13) TFR(15) TFR(26) TFR(6)
  v0 += ks1; v1 += ks2 + 1u;
  TFR(17) TFR(29) TFR(16) TFR(24)
  v0 += ks2; v1 += ks0 + 2u;
  TFR(13) TFR(15) TFR(26) TFR(6)
  v0 += ks0; v1 += ks1 + 3u;
  TFR(17) TFR(29) TFR(16) TFR(24)
  v0 += ks1; v1 += ks2 + 4u;
  TFR(13) TFR(15) TFR(26) TFR(6)
  v0 += ks2; v1 += ks0 + 5u;
#undef TFR
  unsigned bits = (b < 8u) ? v0 : v1;
  float fl = __uint_as_float((bits>>9) | 0x3F800000u) - 1.0f;
  float u = fmaxf(1e-10f, fl + 1e-10f);
  return -logf(-logf(u));
}

// g from 23-bit key, exactly as JAX: fl = as_float(key|0x3f800000)-1
__device__ __forceinline__ float gfromkey(unsigned key){
  float fl = __uint_as_float(key | 0x3F800000u) - 1.0f;
  float u = fmaxf(1e-10f, fl + 1e-10f);
  return -logf(-logf(u));
}

// ---------------- gumbel scan state (split init/iter/finish for thread-granular fusion) ----------------
// Each thread scans 64 values of a 128-chunk (half selected by t&1); lane-pairs
// merge top-2s via shfl_xor(1). packed = (key bits 31..9 in place) | vk where vk
// is the 7-bit *descending* counter (reversed index): integer max = max gumbel,
// ties -> smallest n. Injection adds folded into following round's v0 add.
struct GumState {
  unsigned x0, vk, a1, a2, c1, c2;
  int t;
};

__device__ __forceinline__ void gum_init(GumState& g, int gb){
  g.t = gb*256 + (int)threadIdx.x;
  int half = g.t & 1;
  int m    = (g.t >> 1) & 2047;
  int bl   = (g.t >> 12) & 7;
  int nq   = g.t >> 15;                      // 0..15, chunk of 128
  int nstart = (nq << 7) + (half << 6);      // this thread's 64 values
  g.x0 = ((unsigned)bl << 22) | ((unsigned)nstart << 11) | (unsigned)m;
  g.a1 = g.a2 = g.c1 = g.c2 = 0;
  g.vk = (unsigned)(127 - (half<<6));        // descending; n = chunkbase + 127 - vk
}

__device__ __forceinline__ void gum_iter(GumState& g, const int cnt){
  const unsigned KS2 = 42u ^ 0x1BD11BDAu;
  unsigned x0=g.x0, vk=g.vk, a1=g.a1, a2=g.a2, c1=g.c1, c2=g.c2;
#define TFR(r)       { v0 += v1; v1 = rotl(v1,(r)); v1 ^= v0; }
#define TFRI(r, inj) { v0 += v1 + (inj); v1 = rotl(v1,(r)); v1 ^= v0; }
  #pragma unroll 4
  for (int j = 0; j < cnt; ++j){
    unsigned v0 = x0;
    unsigned v1 = x0 + (HH + 42u);
    TFR(13) TFR(15) TFR(26) TFR(6)
    v1 += KS2 + 1u;
    TFRI(17, 42u) TFR(29) TFR(16) TFR(24)
    v1 += 2u;
    TFRI(13, KS2) TFR(15) TFR(26) TFR(6)
    v1 += 42u + 3u;
    TFR(17) TFR(29) TFR(16) TFR(24)     /* v0 += 0 before this group */
    v1 += KS2 + 4u;
    TFRI(13, 42u) TFR(15) TFR(26) TFR(6)
    v0 += KS2; v1 += 5u;
    unsigned pa = (v0 & 0xFFFFFE00u) | vk;   // v_and_or_b32
    unsigned pb = (v1 & 0xFFFFFE00u) | vk;
    unsigned ta = uminu(pa, a1);
    a1 = umaxu(pa, a1);
    a2 = umaxu(ta, a2);
    unsigned tc = uminu(pb, c1);
    c1 = umaxu(pb, c1);
    c2 = umaxu(tc, c2);
    x0 += 2048u;
    vk -= 1u;
  }
#undef TFR
#undef TFRI
  g.x0=x0; g.vk=vk; g.a1=a1; g.a2=a2; g.c1=c1; g.c2=c2;
}

__device__ __forceinline__ void gum_finish(const GumState& g, float* __restrict__ pcv,
                                           int* __restrict__ pci){
  int half = g.t & 1;
  int m    = (g.t >> 1) & 2047;
  int bl   = (g.t >> 12) & 7;
  int nq   = g.t >> 15;
  int chunkbase = nq << 7;
  // merge with partner lane (other half of the chunk)
  unsigned p1 = __shfl_xor((int)g.a1, 1), p2 = __shfl_xor((int)g.a2, 1);
  unsigned q1 = __shfl_xor((int)g.c1, 1), q2 = __shfl_xor((int)g.c2, 1);
  unsigned A1 = umaxu(g.a1, p1);
  unsigned A2 = umaxu(uminu(g.a1, p1), umaxu(g.a2, p2));
  unsigned C1 = umaxu(g.c1, q1);
  unsigned C2 = umaxu(uminu(g.c1, q1), umaxu(g.c2, q2));
  if (half == 0){
    int baseA = (((nq*NB + bl  )*NN + m) << 1);
    int baseB = (((nq*NB + bl+8)*NN + m) << 1);
    pcv[baseA+0] = gfromkey(A1 >> 9); pci[baseA+0] = chunkbase + 127 - (int)(A1 & 127u);
    pcv[baseA+1] = gfromkey(A2 >> 9); pci[baseA+1] = chunkbase + 127 - (int)(A2 & 127u);
    pcv[baseB+0] = gfromkey(C1 >> 9); pci[baseB+0] = chunkbase + 127 - (int)(C1 & 127u);
    pcv[baseB+1] = gfromkey(C2 >> 9); pci[baseB+1] = chunkbase + 127 - (int)(C2 & 127u);
  }
}

// standalone wrapper (middle tier)
__launch_bounds__(256)
__global__ void kgumbel(float* __restrict__ pcv, int* __restrict__ pci){
  GumState g; gum_init(g, blockIdx.x);
  gum_iter(g, 64);
  gum_finish(g, pcv, pci);
}

// prep finish for 4 rows held in registers: norms (wave shuffle-reduce) + bf16 pack/store
__device__ __forceinline__ void prep_rows(const float4* v, int wid, int lane,
                                          ushort* __restrict__ dst, float* __restrict__ nrm){
  #pragma unroll
  for (int i=0;i<4;i++){
    int row = wid*4 + i;
    float s = v[i].x*v[i].x + v[i].y*v[i].y + v[i].z*v[i].z + v[i].w*v[i].w;
    for (int o=32;o;o>>=1) s += __shfl_down(s,o);
    if (lane==0) nrm[row] = sqrtf(s);
    uint2 u;
    u.x = (__float_as_uint(v[i].y)&0xFFFF0000u)|(__float_as_uint(v[i].x)>>16);
    u.y = (__float_as_uint(v[i].w)&0xFFFF0000u)|(__float_as_uint(v[i].z)>>16);
    int b = row >> 11, nloc = row & 2047;
    int k = lane << 2;
    int ck = k >> 6;
    int j  = k & 63;
    int qi = j >> 3;
    size_t off = (size_t)b*524288 + (size_t)ck*131072 + (size_t)nloc*64
               + ((qi ^ (nloc & 7)) << 3) + (j & 7);
    *(uint2*)(dst + off) = u;
  }
}

// ---------------- row norms (middle tier) ----------------
__global__ void knorms(const float* __restrict__ LLF, const float* __restrict__ HLF,
                       float* __restrict__ nl, float* __restrict__ nh){
  int row = blockIdx.x;
  int wave = threadIdx.x >> 6;
  int lane = threadIdx.x & 63;
  const float* src = wave ? HLF : LLF;
  float4 v = ((const float4*)(src + (size_t)row*ND))[lane];
  float s = v.x*v.x + v.y*v.y + v.z*v.z + v.w*v.w;
  for (int o=32;o;o>>=1) s += __shfl_down(s,o);
  if (lane==0) (wave? nh: nl)[row] = sqrtf(s);
}

// ---------------- fused kernel 1: thread-granular prep-in-gumbel ----------------
// 2048 blocks x 256 threads = 8192 waves = exactly 32 waves/CU: the whole grid is
// resident from t=0 and retires together (no stagger, no tail). Each wave owns
// 4 LLF rows + 4 HLF rows of prep (65536 row-tasks / 8192 waves). Loads are issued
// ahead of a 32-iteration gumbel chunk (~45us of VALU) which hides the HBM latency;
// the reduce/pack/store runs after. VGPR must stay <=64 (8 blocks/CU) -> phase-split
// (4 rows live at a time) + __launch_bounds__(256,8).
__launch_bounds__(256, 8)
__global__ void kfuse1(const float* __restrict__ LLF, const float* __restrict__ HLF,
                       ushort* __restrict__ Abf, ushort* __restrict__ Bbf,
                       float* __restrict__ nl, float* __restrict__ nh,
                       float* __restrict__ pcv, int* __restrict__ pci){
  int t = blockIdx.x*256 + (int)threadIdx.x;
  int wid = t >> 6;
  int lane = t & 63;
  GumState g; gum_init(g, blockIdx.x);
  // phase A: issue LLF loads, run half the gumbel scan, then finish LLF prep
  float4 va[4];
  #pragma unroll
  for (int i=0;i<4;i++)
    va[i] = ((const float4*)(LLF + (size_t)(wid*4+i)*ND))[lane];
  gum_iter(g, 32);
  prep_rows(va, wid, lane, Abf, nl);
  // phase B: issue HLF loads, run the other half, finish HLF prep
  float4 vb[4];
  #pragma unroll
  for (int i=0;i<4;i++)
    vb[i] = ((const float4*)(HLF + (size_t)(wid*4+i)*ND))[lane];
  gum_iter(g, 32);
  prep_rows(vb, wid, lane, Bbf, nh);
  gum_finish(g, pcv, pci);
}

// ---------------- bf16 MFMA GEMM with global_load_lds staging ----------------
#define K1 0.09016844f   /* 0.0625 * log2(e) */
__launch_bounds__(256)
__global__ void kgemm_dma(const ushort* __restrict__ Abf, const ushort* __restrict__ Bbf,
                          const float* __restrict__ nl, const float* __restrict__ nh,
                          float* __restrict__ partS){
  __shared__ ushort As[128*64];   // 16 KB, [row][64] with XOR-swizzled quads
  __shared__ ushort Bs[128*64];
  __shared__ float colsum[128];
  const int b  = blockIdx.z;
  const int n0 = blockIdx.y << 7;
  const int m0 = blockIdx.x << 7;
  const int tid  = threadIdx.x;
  const int lane = tid & 63;
  const int w    = tid >> 6;
  const int wn   = w >> 1, wm = w & 1;
  const int quad = lane >> 4, l15 = lane & 15;
  if (tid < 128) colsum[tid] = 0.0f;

  const ushort* Ab = Abf + (size_t)b*524288;
  const ushort* Bb = Bbf + (size_t)b*524288;

  f32x4 acc[4][4];
  #pragma unroll
  for (int i=0;i<4;i++)
    #pragma unroll
    for (int j=0;j<4;j++) acc[i][j] = (f32x4){0.f,0.f,0.f,0.f};

  for (int ck=0; ck<4; ck++){
    __syncthreads();
    const ushort* ga = Ab + (size_t)ck*131072 + (size_t)n0*64;  // 16 KB contiguous
    const ushort* gb = Bb + (size_t)ck*131072 + (size_t)m0*64;
    #pragma unroll
    for (int t=0;t<4;t++){
      int seg = (w*4 + t) * 512;              // 512 ushorts = 1 KB per wave-load
      gld16(ga + seg + lane*8, &As[seg]);
      gld16(gb + seg + lane*8, &Bs[seg]);
    }
    __syncthreads();
    #pragma unroll
    for (int ks=0; ks<64; ks+=32){
      bf16x8 af[4], bf[4];
      #pragma unroll
      for (int t=0;t<4;t++){
        int R = wn*64 + t*16 + l15;
        af[t] = *(const bf16x8*)(&As[R*64 + ((((ks>>3)+quad) ^ (R&7))<<3)]);
      }
      #pragma unroll
      for (int t=0;t<4;t++){
        int R = wm*64 + t*16 + l15;
        bf[t] = *(const bf16x8*)(&Bs[R*64 + ((((ks>>3)+quad) ^ (R&7))<<3)]);
      }
      #pragma unroll
      for (int ti=0;ti<4;ti++)
        #pragma unroll
        for (int tj=0;tj<4;tj++)
          acc[ti][tj] = __builtin_amdgcn_mfma_f32_16x16x32_bf16(af[ti], bf[tj], acc[ti][tj], 0, 0, 0);
    }
  }

  float an[4][4];
  #pragma unroll
  for (int ti=0;ti<4;ti++)
    #pragma unroll
    for (int r=0;r<4;r++)
      an[ti][r] = K1 / nl[b*NN + n0 + wn*64 + ti*16 + quad*4 + r];
  float bm[4];
  #pragma unroll
  for (int tj=0;tj<4;tj++)
    bm[tj] = 1.0f / nh[b*NN + m0 + wm*64 + tj*16 + l15];
  #pragma unroll
  for (int tj=0;tj<4;tj++){
    float s = 0.0f;
    #pragma unroll
    for (int ti=0;ti<4;ti++)
      #pragma unroll
      for (int r=0;r<4;r++)
        s += __builtin_amdgcn_exp2f(acc[ti][tj][r]*an[ti][r]*bm[tj] - K1);
    s += __shfl_down(s, 32);
    s += __shfl_down(s, 16);
    if (lane < 16) atomicAdd(&colsum[wm*64 + tj*16 + l15], s);
  }
  __syncthreads();
  if (tid < 128)
    partS[(size_t)blockIdx.y*BNtot + b*NN + m0 + tid] = colsum[tid];
}

// ---------------- middle-tier GEMM (in-kernel conversion) ----------------
__launch_bounds__(256)
__global__ void kgemm_mfma(const float* __restrict__ LLF, const float* __restrict__ HLF,
                           const float* __restrict__ nl, const float* __restrict__ nh,
                           float* __restrict__ partS){
  __shared__ ushort As[128][72];
  __shared__ ushort Bs[128][72];
  __shared__ float colsum[128];
  const int b  = blockIdx.z;
  const int n0 = blockIdx.y << 7;
  const int m0 = blockIdx.x << 7;
  const float* Ab = LLF + (size_t)b*NN*ND;
  const float* Bb = HLF + (size_t)b*NN*ND;
  const int tid  = threadIdx.x;
  const int lane = tid & 63;
  const int w    = tid >> 6;
  const int wn   = w >> 1, wm = w & 1;
  const int quad = lane >> 4, l15 = lane & 15;
  if (tid < 128) colsum[tid] = 0.0f;

  f32x4 acc[4][4];
  #pragma unroll
  for (int i=0;i<4;i++)
    #pragma unroll
    for (int j=0;j<4;j++) acc[i][j] = (f32x4){0.f,0.f,0.f,0.f};

  const int rbase = tid >> 3;
  const int kq    = (tid & 7) << 3;

  for (int ck=0; ck<4; ck++){
    const int k0 = ck << 6;
    __syncthreads();
    #pragma unroll
    for (int pi=0; pi<4; pi++){
      int row = rbase + (pi<<5);
      const float* pa = Ab + (size_t)(n0+row)*ND + k0 + kq;
      float4 a0 = *(const float4*)pa;
      float4 a1 = *(const float4*)(pa+4);
      uint4 ua;
      ua.x = (__float_as_uint(a0.y)&0xFFFF0000u)|(__float_as_uint(a0.x)>>16);
      ua.y = (__float_as_uint(a0.w)&0xFFFF0000u)|(__float_as_uint(a0.z)>>16);
      ua.z = (__float_as_uint(a1.y)&0xFFFF0000u)|(__float_as_uint(a1.x)>>16);
      ua.w = (__float_as_uint(a1.w)&0xFFFF0000u)|(__float_as_uint(a1.z)>>16);
      *(uint4*)(&As[row][kq]) = ua;
      const float* pb = Bb + (size_t)(m0+row)*ND + k0 + kq;
      float4 b0 = *(const float4*)pb;
      float4 b1 = *(const float4*)(pb+4);
      uint4 ub;
      ub.x = (__float_as_uint(b0.y)&0xFFFF0000u)|(__float_as_uint(b0.x)>>16);
      ub.y = (__float_as_uint(b0.w)&0xFFFF0000u)|(__float_as_uint(b0.z)>>16);
      ub.z = (__float_as_uint(b1.y)&0xFFFF0000u)|(__float_as_uint(b1.x)>>16);
      ub.w = (__float_as_uint(b1.w)&0xFFFF0000u)|(__float_as_uint(b1.z)>>16);
      *(uint4*)(&Bs[row][kq]) = ub;
    }
    __syncthreads();
    #pragma unroll
    for (int ks=0; ks<64; ks+=32){
      bf16x8 af[4], bf[4];
      #pragma unroll
      for (int t=0;t<4;t++)
        af[t] = *(const bf16x8*)(&As[wn*64 + t*16 + l15][ks + quad*8]);
      #pragma unroll
      for (int t=0;t<4;t++)
        bf[t] = *(const bf16x8*)(&Bs[wm*64 + t*16 + l15][ks + quad*8]);
      #pragma unroll
      for (int ti=0;ti<4;ti++)
        #pragma unroll
        for (int tj=0;tj<4;tj++)
          acc[ti][tj] = __builtin_amdgcn_mfma_f32_16x16x32_bf16(af[ti], bf[tj], acc[ti][tj], 0, 0, 0);
    }
  }

  float an[4][4];
  #pragma unroll
  for (int ti=0;ti<4;ti++)
    #pragma unroll
    for (int r=0;r<4;r++)
      an[ti][r] = K1 / nl[b*NN + n0 + wn*64 + ti*16 + quad*4 + r];
  float bm[4];
  #pragma unroll
  for (int tj=0;tj<4;tj++)
    bm[tj] = 1.0f / nh[b*NN + m0 + wm*64 + tj*16 + l15];
  #pragma unroll
  for (int tj=0;tj<4;tj++){
    float s = 0.0f;
    #pragma unroll
    for (int ti=0;ti<4;ti++)
      #pragma unroll
      for (int r=0;r<4;r++)
        s += __builtin_amdgcn_exp2f(acc[ti][tj][r]*an[ti][r]*bm[tj] - K1);
    s += __shfl_down(s, 32);
    s += __shfl_down(s, 16);
    if (lane < 16) atomicAdd(&colsum[wm*64 + tj*16 + l15], s);
  }
  __syncthreads();
  if (tid < 128)
    partS[(size_t)blockIdx.y*BNtot + b*NN + m0 + tid] = colsum[tid];
}

// ---------------- resolve: exact argmax among windowed candidates (inlines partS sum) ----------------
__launch_bounds__(256)
__global__ void kresolve(const float* __restrict__ LLF, const float* __restrict__ HLF,
                         const float* __restrict__ nl, const float* __restrict__ nh,
                         const float* __restrict__ partS,
                         const float* __restrict__ pcv, const int* __restrict__ pci,
                         int* __restrict__ idx){
  int w    = threadIdx.x >> 6;               // wave within block
  int lane = threadIdx.x & 63;
  int g = blockIdx.x*4 + w;                  // b*NN+m
  int b = g >> 11, m = g & 2047;
  // softmax denominator: sum 16 partial tiles (was kScomb)
  float ps = (lane < 16) ? partS[(size_t)lane*BNtot + g] : 0.0f;
  ps += __shfl_down(ps, 8);
  ps += __shfl_down(ps, 4);
  ps += __shfl_down(ps, 2);
  ps += __shfl_down(ps, 1);
  float invS = 1.0f / __shfl(ps, 0);
  float pv = -INFINITY; int pn = 0;
  if (lane < 32){                            // nq = lane>>1, rank = lane&1
    int base = ((((lane>>1)*NB + b)*NN + m) << 1) + (lane & 1);
    pv = pcv[base]; pn = pci[base];
  }
  float gmax = pv;
  for (int o=32;o;o>>=1) gmax = fmaxf(gmax, __shfl_down(gmax,o));
  gmax = __shfl(gmax, 0);
  unsigned long long mask = __ballot(pv >= gmax - 8e-5f);
  mask &= 0xFFFFFFFFull;
  float4 h = ((const float4*)(HLF + (size_t)g*ND))[lane];   // loop-invariant row m
  float nhg = nh[g];
  float bestQ = -INFINITY; int bestN = 1<<30;
  while (mask){
    int src = __builtin_ctzll(mask); mask &= mask-1;
    int   n  = __shfl(pn, src);
    float gv = __shfl(pv, src);
    float4 a = ((const float4*)(LLF + ((size_t)b*NN + n)*ND))[lane];
    float d = a.x*h.x + a.y*h.y + a.z*h.z + a.w*h.w;
    for (int o=32;o;o>>=1) d += __shfl_down(d,o);
    d = __shfl(d, 0);
    float sim = (d / fmaxf(nl[b*NN+n]*nhg, 1e-8f)) * 0.0625f;
    float q = expf(sim - 0.0625f)*invS + gv;
    if (q > bestQ || (q == bestQ && n < bestN)){ bestQ = q; bestN = n; }
  }
  if (lane==0) idx[g] = bestN;
}

// ---------------- last-resort fallback (tiny ws) ----------------
__launch_bounds__(256)
__global__ void kstats(const float* __restrict__ A, const float* __restrict__ Bm,
                       const float* __restrict__ nl, const float* __restrict__ nh,
                       float* __restrict__ Mout, float* __restrict__ Sinv){
  __shared__ float As[64][33];
  __shared__ float Bs[64][33];
  __shared__ float Cs[64][65];
  const int b  = blockIdx.x >> 5;
  const int m0 = (blockIdx.x & 31) << 6;
  const float* Ab = A  + (size_t)b*NN*ND;
  const float* Bb = Bm + (size_t)b*NN*ND;
  const int tid = threadIdx.x;
  const int tx = tid & 15, ty = tid >> 4;
  float nhv[4];
  #pragma unroll
  for (int j=0;j<4;j++) nhv[j] = nh[b*NN + m0 + tx*4 + j];
  float Mr = -INFINITY, Sr = 0.0f;
  for (int nt=0; nt<NN; nt+=64){
    float acc[4][4] = {{0.f,0.f,0.f,0.f},{0.f,0.f,0.f,0.f},{0.f,0.f,0.f,0.f},{0.f,0.f,0.f,0.f}};
    for (int kc=0; kc<ND; kc+=32){
      __syncthreads();
      #pragma unroll
      for (int s=0;s<2;s++){
        int f = tid + (s<<8);
        int r = f >> 3;
        int c = (f & 7) << 2;
        float4 va = *(const float4*)(Ab + (size_t)(nt+r)*ND + kc + c);
        As[r][c]=va.x; As[r][c+1]=va.y; As[r][c+2]=va.z; As[r][c+3]=va.w;
        float4 vb = *(const float4*)(Bb + (size_t)(m0+r)*ND + kc + c);
        Bs[r][c]=vb.x; Bs[r][c+1]=vb.y; Bs[r][c+2]=vb.z; Bs[r][c+3]=vb.w;
      }
      __syncthreads();
      #pragma unroll 4
      for (int k=0;k<32;k++){
        float a0=As[ty*4+0][k], a1=As[ty*4+1][k], a2=As[ty*4+2][k], a3=As[ty*4+3][k];
        float b0=Bs[tx*4+0][k], b1=Bs[tx*4+1][k], b2=Bs[tx*4+2][k], b3=Bs[tx*4+3][k];
        acc[0][0]+=a0*b0; acc[0][1]+=a0*b1; acc[0][2]+=a0*b2; acc[0][3]+=a0*b3;
        acc[1][0]+=a1*b0; acc[1][1]+=a1*b1; acc[1][2]+=a1*b2; acc[1][3]+=a1*b3;
        acc[2][0]+=a2*b0; acc[2][1]+=a2*b1; acc[2][2]+=a2*b2; acc[2][3]+=a2*b3;
        acc[3][0]+=a3*b0; acc[3][1]+=a3*b1; acc[3][2]+=a3*b2; acc[3][3]+=a3*b3;
      }
    }
    float nlv[4];
    #pragma unroll
    for (int i=0;i<4;i++) nlv[i] = nl[b*NN + nt + ty*4 + i];
    __syncthreads();
    #pragma unroll
    for (int i=0;i<4;i++)
      #pragma unroll
      for (int j=0;j<4;j++){
        float denom = fmaxf(nlv[i]*nhv[j], 1e-8f);
        Cs[ty*4+i][tx*4+j] = (acc[i][j]/denom)*0.0625f;
      }
    __syncthreads();
    if (tid < 64){
      float tmax = -INFINITY;
      #pragma unroll 8
      for (int r=0;r<64;r++) tmax = fmaxf(tmax, Cs[r][tid]);
      float newM = fmaxf(Mr, tmax);
      float s = 0.0f;
      #pragma unroll 4
      for (int r=0;r<64;r++) s += expf(Cs[r][tid]-newM);
      Sr = Sr*expf(Mr-newM) + s;
      Mr = newM;
    }
  }
  if (tid < 64){
    Mout[b*NN+m0+tid] = Mr;
    Sinv[b*NN+m0+tid] = 1.0f/Sr;
  }
}

__launch_bounds__(256)
__global__ void kargmax(const float* __restrict__ A, const float* __restrict__ Bm,
                        const float* __restrict__ nl, const float* __restrict__ nh,
                        const float* __restrict__ Mv, const float* __restrict__ Sv,
                        int* __restrict__ idxout){
  __shared__ float As[64][33];
  __shared__ float Bs[64][33];
  __shared__ float Vs[16][64];
  __shared__ int   Is[16][64];
  const int b  = blockIdx.x >> 5;
  const int m0 = (blockIdx.x & 31) << 6;
  const float* Ab = A  + (size_t)b*NN*ND;
  const float* Bb = Bm + (size_t)b*NN*ND;
  const int tid = threadIdx.x;
  const int tx = tid & 15, ty = tid >> 4;
  float nhv[4], Mj[4], iSj[4];
  #pragma unroll
  for (int j=0;j<4;j++){
    int m = m0 + tx*4 + j;
    nhv[j] = nh[b*NN + m];
    Mj[j]  = Mv[b*NN + m];
    iSj[j] = Sv[b*NN + m];
  }
  float bestV = -INFINITY; int bestN = 0;
  for (int nt=0; nt<NN; nt+=64){
    float acc[4][4] = {{0.f,0.f,0.f,0.f},{0.f,0.f,0.f,0.f},{0.f,0.f,0.f,0.f},{0.f,0.f,0.f,0.f}};
    for (int kc=0; kc<ND; kc+=32){
      __syncthreads();
      #pragma unroll
      for (int s=0;s<2;s++){
        int f = tid + (s<<8);
        int r = f >> 3;
        int c = (f & 7) << 2;
        float4 va = *(const float4*)(Ab + (size_t)(nt+r)*ND + kc + c);
        As[r][c]=va.x; As[r][c+1]=va.y; As[r][c+2]=va.z; As[r][c+3]=va.w;
        float4 vb = *(const float4*)(Bb + (size_t)(m0+r)*ND + kc + c);
        Bs[r][c]=vb.x; Bs[r][c+1]=vb.y; Bs[r][c+2]=vb.z; Bs[r][c+3]=vb.w;
      }
      __syncthreads();
      #pragma unroll 4
      for (int k=0;k<32;k++){
        float a0=As[ty*4+0][k], a1=As[ty*4+1][k], a2=As[ty*4+2][k], a3=As[ty*4+3][k];
        float b0=Bs[tx*4+0][k], b1=Bs[tx*4+1][k], b2=Bs[tx*4+2][k], b3=Bs[tx*4+3][k];
        acc[0][0]+=a0*b0; acc[0][1]+=a0*b1; acc[0][2]+=a0*b2; acc[0][3]+=a0*b3;
        acc[1][0]+=a1*b0; acc[1][1]+=a1*b1; acc[1][2]+=a1*b2; acc[1][3]+=a1*b3;
        acc[2][0]+=a2*b0; acc[2][1]+=a2*b1; acc[2][2]+=a2*b2; acc[2][3]+=a2*b3;
        acc[3][0]+=a3*b0; acc[3][1]+=a3*b1; acc[3][2]+=a3*b2; acc[3][3]+=a3*b3;
      }
    }
    float nlv[4];
    #pragma unroll
    for (int i=0;i<4;i++) nlv[i] = nl[b*NN + nt + ty*4 + i];
    float lv[4]; int li[4];
    #pragma unroll
    for (int j=0;j<4;j++){ lv[j] = -INFINITY; li[j] = 0; }
    #pragma unroll
    for (int i=0;i<4;i++){
      int n = nt + ty*4 + i;
      #pragma unroll
      for (int j=0;j<4;j++){
        float denom = fmaxf(nlv[i]*nhv[j], 1e-8f);
        float sim = (acc[i][j]/denom)*0.0625f;
        float p = expf(sim - Mj[j]) * iSj[j];
        float v = p + gumbelv((unsigned)b, (unsigned)n, (unsigned)(m0 + tx*4 + j));
        if (v > lv[j]) { lv[j] = v; li[j] = n; }
      }
    }
    __syncthreads();
    #pragma unroll
    for (int j=0;j<4;j++){ Vs[ty][tx*4+j]=lv[j]; Is[ty][tx*4+j]=li[j]; }
    __syncthreads();
    if (tid < 64){
      #pragma unroll 4
      for (int t=0;t<16;t++){
        float v = Vs[t][tid];
        if (v > bestV){ bestV = v; bestN = Is[t][tid]; }
      }
    }
  }
  if (tid < 64) idxout[b*NN + m0 + tid] = bestN;
}

// ---------------- shared tail kernels ----------------
__global__ void ksort(const int* __restrict__ idx, int* __restrict__ cntg,
                      int* __restrict__ offg, int* __restrict__ sl){
  __shared__ int c[NN];
  __shared__ int part[256];
  int b = blockIdx.x, tid = threadIdx.x;
  for (int v=tid; v<NN; v+=256) c[v]=0;
  __syncthreads();
  for (int j=tid; j<NN; j+=256) atomicAdd(&c[idx[b*NN+j]], 1);
  __syncthreads();
  int base = tid*8, s=0, lc[8];
  #pragma unroll
  for (int k=0;k<8;k++){ lc[k]=c[base+k]; s+=lc[k]; }
  part[tid]=s; __syncthreads();
  for (int o=1;o<256;o<<=1){
    int v = (tid>=o)? part[tid-o] : 0;
    __syncthreads();
    part[tid]+=v;
    __syncthreads();
  }
  int run = part[tid]-s;
  #pragma unroll
  for (int k=0;k<8;k++){
    int v = base+k;
    cntg[b*NN+v]=lc[k];
    offg[b*NN+v]=run;
    for (int j=0;j<lc[k];j++) sl[b*NN+run+j]=v;
    run += lc[k];
  }
}

__global__ void kw(const float* __restrict__ LLF, const float* __restrict__ HLF,
                   const float* __restrict__ nl, const float* __restrict__ nh,
                   const int* __restrict__ sl, float* __restrict__ w){
  int g = blockIdx.x*4 + (threadIdx.x>>6);
  int lane = threadIdx.x & 63;
  int b = g >> 11;
  int s = sl[g];
  float4 a = ((const float4*)(HLF + ((size_t)b*NN + s)*ND))[lane];
  float4 l = ((const float4*)(LLF + (size_t)g*ND))[lane];
  float d = a.x*l.x + a.y*l.y + a.z*l.z + a.w*l.w;
  for (int o=32;o;o>>=1) d += __shfl_down(d,o);
  if (lane==0){
    float denom = fmaxf(nh[b*NN+s]*nl[g], 1e-8f);
    w[g] = d/denom;
  }
}

__global__ void knoise(const float* __restrict__ w, float* __restrict__ nz){
  int b = blockIdx.x, tid = threadIdx.x;
  __shared__ float sred[4];
  float x[8]; float mx = -INFINITY;
  #pragma unroll
  for (int k=0;k<8;k++){ x[k] = w[b*NN + tid*8 + k] / 0.1f; mx = fmaxf(mx, x[k]); }
  for (int o=32;o;o>>=1) mx = fmaxf(mx, __shfl_down(mx,o));
  mx = __shfl(mx, 0);
  if ((tid&63)==0) sred[tid>>6] = mx;
  __syncthreads();
  mx = fmaxf(fmaxf(sred[0],sred[1]), fmaxf(sred[2],sred[3]));
  __syncthreads();
  float e[8]; float s = 0.f;
  #pragma unroll
  for (int k=0;k<8;k++){ e[k] = expf(x[k]-mx); s += e[k]; }
  for (int o=32;o;o>>=1) s += __shfl_down(s,o);
  s = __shfl(s, 0);
  if ((tid&63)==0) sred[tid>>6] = s;
  __syncthreads();
  s = sred[0]+sred[1]+sred[2]+sred[3];
  #pragma unroll
  for (int k=0;k<8;k++) nz[b*NN + tid*8 + k] = e[k]/s;
}

__global__ void kfinal(const float* __restrict__ LLF, const float* __restrict__ HLF,
                       const int* __restrict__ cnt, const int* __restrict__ off,
                       const float* __restrict__ nz, float* __restrict__ out){
  int row = blockIdx.x;
  int lane = threadIdx.x;
  int b = row >> 11;
  float4 h = ((const float4*)(HLF + (size_t)row*ND))[lane];
  int c = cnt[row];
  if (c > 0){
    int i = off[row] + c - 1;
    float ns = nz[b*NN + i];
    float4 l = ((const float4*)(LLF + ((size_t)(b*NN + i))*ND))[lane];
    h.x += l.x*ns; h.y += l.y*ns; h.z += l.z*ns; h.w += l.w*ns;
  }
  ((float4*)(out + (size_t)row*ND))[lane] = h;
}

extern "C" void kernel_launch(void* const* d_in, const int* in_sizes, int n_in,
                              void* d_out, int out_size, void* d_ws, size_t ws_size,
                              hipStream_t stream){
  const float* LLF = (const float*)d_in[0];
  const float* HLF = (const float*)d_in[1];
  float* out = (float*)d_out;
  float* ws = (float*)d_ws;

  float* nl  = ws;
  float* nh  = ws + 1*(size_t)BNtot;
  float* iS  = ws + 2*(size_t)BNtot;
  int*   idx = (int*)(ws + 3*(size_t)BNtot);
  int*   cnt = (int*)(ws + 4*(size_t)BNtot);
  int*   off = (int*)(ws + 5*(size_t)BNtot);
  int*   sl  = (int*)(ws + 6*(size_t)BNtot);
  float* wv  = ws + 7*(size_t)BNtot;
  float* nz  = ws + 8*(size_t)BNtot;
  float* partS = ws + 9*(size_t)BNtot;                 // 16*BNtot
  float* pcv   = partS + 16*(size_t)BNtot;             // 32*BNtot (16 chunks x 2 ranks)
  int*   pci   = (int*)(pcv + 32*(size_t)BNtot);       // 32*BNtot
  ushort* Abf  = (ushort*)(pci + 32*(size_t)BNtot);    // BNtot*256 bf16 (16.7 MB)
  ushort* Bbf  = Abf + (size_t)BNtot*ND;
  const size_t needBytes1 = (9 + 16 + 32 + 32) * (size_t)BNtot * 4;           // ~11.7 MB
  const size_t needBytes2 = needBytes1 + 2 * (size_t)BNtot * ND * 2;          // ~45.2 MB

  if (ws_size >= needBytes2){
    // [prep inside gumbel threads] -> gemm -> resolve (inlines Scomb)
    hipLaunchKernelGGL(kfuse1,  dim3(2048),      dim3(256), 0, stream, LLF, HLF, Abf, Bbf, nl, nh, pcv, pci);
    hipLaunchKernelGGL(kgemm_dma,dim3(16,16,16), dim3(256), 0, stream, Abf, Bbf, nl, nh, partS);
    hipLaunchKernelGGL(kresolve,dim3(BNtot/4),   dim3(256), 0, stream, LLF, HLF, nl, nh, partS, pcv, pci, idx);
  } else if (ws_size >= needBytes1){
    hipLaunchKernelGGL(knorms,   dim3(BNtot),      dim3(128), 0, stream, LLF, HLF, nl, nh);
    hipLaunchKernelGGL(kgemm_mfma,dim3(16,16,16),  dim3(256), 0, stream, LLF, HLF, nl, nh, partS);
    hipLaunchKernelGGL(kgumbel,  dim3(2048),       dim3(256), 0, stream, pcv, pci);
    hipLaunchKernelGGL(kresolve, dim3(BNtot/4),    dim3(256), 0, stream, LLF, HLF, nl, nh, partS, pcv, pci, idx);
  } else {
    float* Mv = ws + 9*(size_t)BNtot;
    hipLaunchKernelGGL(knorms,   dim3(BNtot),      dim3(128), 0, stream, LLF, HLF, nl, nh);
    hipLaunchKernelGGL(kstats,   dim3(NB*32),      dim3(256), 0, stream, LLF, HLF, nl, nh, Mv, iS);
    hipLaunchKernelGGL(kargmax,  dim3(NB*32),      dim3(256), 0, stream, LLF, HLF, nl, nh, Mv, iS, idx);
  }

  hipLaunchKernelGGL(ksort,  dim3(NB),      dim3(256), 0, stream, idx, cnt, off, sl);
  hipLaunchKernelGGL(kw,     dim3(BNtot/4), dim3(256), 0, stream, LLF, HLF, nl, nh, sl, wv);
  hipLaunchKernelGGL(knoise, dim3(NB),      dim3(256), 0, stream, wv, nz);
  hipLaunchKernelGGL(kfinal, dim3(BNtot),   dim3(64),  0, stream, LLF, HLF, cnt, off, nz, out);
}